// Round 13
// baseline (773.015 us; speedup 1.0000x reference)
//
#include <hip/hip_runtime.h>
#include <cstddef>
#include <cstdint>

#define NN 12288
#define FF 512
#define NWORDS (NN / 32)   // 384 mask words per row
#define NKT (NN / 128)     // 96 key tiles
#define CMP_BLOCKS ((NN * NWORDS) / 256)   // 18432 compress blocks
#define PREP_BLOCKS ((NN / 32) * (FF / 32)) // 6144 prep blocks

using half8 = __attribute__((ext_vector_type(8))) _Float16;
using half4 = __attribute__((ext_vector_type(4))) _Float16;
using f32x4 = __attribute__((ext_vector_type(4))) float;

constexpr float MASK_NEG = -1e9f;  // Keras additive mask constant

// ---- async global->LDS 16B helper (wave-uniform LDS base; HW adds lane*16;
//      the GLOBAL source address is per-lane) ----
__device__ __forceinline__ void gll16(const void* g, void* l) {
    __builtin_amdgcn_global_load_lds((const __attribute__((address_space(1))) void*)g,
                                     (__attribute__((address_space(3))) void*)l, 16, 0, 0);
}

// counted-vmcnt phase sync (r8-verified): wait until <=N VMEM outstanding,
// barrier, pin following ds_reads below the barrier.
#define PHASE(N)                                                        \
    do {                                                                \
        asm volatile("s_waitcnt vmcnt(" #N ")" ::: "memory");           \
        __builtin_amdgcn_s_barrier();                                   \
        __builtin_amdgcn_sched_barrier(0);                              \
    } while (0)

// ---------------- fused prepass: A->bitmask  +  feath/featT (role-split) ----------------
// Blocks [0, CMP_BLOCKS): compress 604 MB A -> 18.9 MB bitmask (pure BW).
// Blocks [CMP_BLOCKS, +PREP_BLOCKS): fp32->fp16 row copy + 32x32 transpose.
// prep's 50 MB rides in compress's bandwidth shadow -> ~one A-read of wall time.
__global__ __launch_bounds__(256)
void prepass_fused(const int* __restrict__ Amat, uint32_t* __restrict__ Abits,
                   const float* __restrict__ in, _Float16* __restrict__ feath,
                   _Float16* __restrict__ featT) {
    const int bid = blockIdx.x;
    if (bid < CMP_BLOCKS) {
        const size_t W = (size_t)bid * 256 + threadIdx.x;  // word index
        const int4* p = reinterpret_cast<const int4*>(Amat + W * 32);
        uint32_t b = 0;
#pragma unroll
        for (int q = 0; q < 8; ++q) {
            const int4 v = p[q];
            b |= (uint32_t)(v.x > 0) << (4 * q + 0);
            b |= (uint32_t)(v.y > 0) << (4 * q + 1);
            b |= (uint32_t)(v.z > 0) << (4 * q + 2);
            b |= (uint32_t)(v.w > 0) << (4 * q + 3);
        }
        Abits[W] = b;
    } else {
        __shared__ float tile[32][33];
        const int b2 = bid - CMP_BLOCKS;
        const int bi = b2 % (NN / 32);          // n-tile (384)
        const int bj = b2 / (NN / 32);          // f-tile (16)
        const int r  = threadIdx.x >> 3;
        const int c4 = (threadIdx.x & 7) << 2;
        float4 v = *reinterpret_cast<const float4*>(in + (size_t)(bi * 32 + r) * FF + bj * 32 + c4);
        tile[r][c4 + 0] = v.x; tile[r][c4 + 1] = v.y; tile[r][c4 + 2] = v.z; tile[r][c4 + 3] = v.w;
        half4 hr;
        hr[0] = (_Float16)v.x; hr[1] = (_Float16)v.y; hr[2] = (_Float16)v.z; hr[3] = (_Float16)v.w;
        *reinterpret_cast<half4*>(feath + (size_t)(bi * 32 + r) * FF + bj * 32 + c4) = hr;
        __syncthreads();   // uniform per block (whole block takes this branch)
        half4 h;
#pragma unroll
        for (int k = 0; k < 4; ++k) h[k] = (_Float16)tile[c4 + k][r];
        *reinterpret_cast<half4*>(featT + (size_t)(bj * 32 + r) * NN + bi * 32 + c4) = h;
    }
}

// ---------------- prepass (fallback only): features fp32 -> fp16 row-major ----------------
__global__ void cvt_feat_kernel(const float* __restrict__ in, _Float16* __restrict__ out) {
    const size_t i = ((size_t)blockIdx.x * blockDim.x + threadIdx.x) * 8;
    float4 x = *reinterpret_cast<const float4*>(in + i);
    float4 y = *reinterpret_cast<const float4*>(in + i + 4);
    half8 h;
    h[0] = (_Float16)x.x; h[1] = (_Float16)x.y; h[2] = (_Float16)x.z; h[3] = (_Float16)x.w;
    h[4] = (_Float16)y.x; h[5] = (_Float16)y.y; h[6] = (_Float16)y.z; h[7] = (_Float16)y.w;
    *reinterpret_cast<half8*>(out + i) = h;
}

// ---------------- GEMM1: S=F*F^T, bit-mask epilogue, rowmax, P'=exp(s-m_t), rowsum ----------------
// r12-verbatim (counted PHASE pipeline + swizzle; measured ~334 us).
__global__ __launch_bounds__(256)
void gemm1_exp(const _Float16* __restrict__ feath, const uint32_t* __restrict__ Abits,
               _Float16* __restrict__ Pmat, float* __restrict__ m_t, _Float16* __restrict__ s_t) {
    __shared__ alignas(16) _Float16 As[3][128 * 32];
    __shared__ alignas(16) _Float16 Bs[3][128 * 32];
    __shared__ alignas(16) float rowmax2[128][2];
    __shared__ alignas(16) float rowsum2[128][2];

    const int tid = threadIdx.x, lane = tid & 63, wid = tid >> 6;
    const int g = lane >> 4, a = lane & 15;
    const int wr = wid >> 1, wc = wid & 1;
    const int row0 = blockIdx.x * 128, col0 = blockIdx.y * 128;

    f32x4 acc[4][4];
#pragma unroll
    for (int i = 0; i < 4; ++i)
#pragma unroll
        for (int j = 0; j < 4; ++j) acc[i][j] = f32x4{0.f, 0.f, 0.f, 0.f};

    const int lr  = lane >> 2;                    // 0..15 row within 16-row chunk
    const int sl  = lane & 3;                     // physical 16B slot this lane fills
    const int lsw = (sl ^ ((lr >> 1) & 3)) * 8;   // pre-swizzled logical f16 offset
    const int rk  = (a >> 1) & 3;                 // read-side XOR key (row>>1)&3

    auto stage = [&](int buf, int t) {
#pragma unroll
        for (int c = 0; c < 2; ++c) {
            const int ch = wid * 2 + c;  // 0..7
            gll16(feath + (size_t)(row0 + ch * 16 + lr) * FF + t * 32 + lsw, &As[buf][ch * 512]);
            gll16(feath + (size_t)(col0 + ch * 16 + lr) * FF + t * 32 + lsw, &Bs[buf][ch * 512]);
        }
    };

    stage(0, 0);
    stage(1, 1);          // outstanding: 8
#pragma unroll
    for (int t = 0; t < 16; ++t) {
        if (t < 15) PHASE(4);   // retire buffer t's 4 loads; keep t+1 in flight
        else        PHASE(0);
        const int cb = t % 3;
        half8 af[4], bf[4];
#pragma unroll
        for (int rf = 0; rf < 4; ++rf)
            af[rf] = *reinterpret_cast<const half8*>(&As[cb][(64 * wr + 16 * rf + a) * 32 + ((g ^ rk) << 3)]);
#pragma unroll
        for (int cf = 0; cf < 4; ++cf)
            bf[cf] = *reinterpret_cast<const half8*>(&Bs[cb][(64 * wc + 16 * cf + a) * 32 + ((g ^ rk) << 3)]);
#pragma unroll
        for (int rf = 0; rf < 4; ++rf)
#pragma unroll
            for (int cf = 0; cf < 4; ++cf)
                acc[rf][cf] = __builtin_amdgcn_mfma_f32_16x16x32_f16(af[rf], bf[cf], acc[rf][cf], 0, 0, 0);
        if (t + 2 < 16) stage((t + 2) % 3, t + 2);
    }

    // ---- mask from bit-matrix: 16 broadcast uint2 loads (L3-resident 19 MB) ----
    const int cw0 = (col0 + 64 * wc) >> 5;   // even word index -> 8B aligned
    uint2 am[4][4];
#pragma unroll
    for (int rf = 0; rf < 4; ++rf)
#pragma unroll
        for (int r = 0; r < 4; ++r) {
            const int grow = row0 + 64 * wr + 16 * rf + 4 * g + r;
            am[rf][r] = *reinterpret_cast<const uint2*>(&Abits[(size_t)grow * NWORDS + cw0]);
        }
#pragma unroll
    for (int rf = 0; rf < 4; ++rf)
#pragma unroll
        for (int r = 0; r < 4; ++r)
#pragma unroll
            for (int cf = 0; cf < 4; ++cf) {
                const uint32_t w = (cf < 2) ? am[rf][r].x : am[rf][r].y;
                const uint32_t bit = (w >> (a + 16 * (cf & 1))) & 1u;
                acc[rf][cf][r] = bit ? acc[rf][cf][r] : MASK_NEG;
            }

    // ---- per-row tile max (16 col-lanes reduce, halves via LDS) ----
#pragma unroll
    for (int rf = 0; rf < 4; ++rf)
#pragma unroll
        for (int r = 0; r < 4; ++r) {
            float v = fmaxf(fmaxf(acc[rf][0][r], acc[rf][1][r]), fmaxf(acc[rf][2][r], acc[rf][3][r]));
            v = fmaxf(v, __shfl_xor(v, 1, 16));
            v = fmaxf(v, __shfl_xor(v, 2, 16));
            v = fmaxf(v, __shfl_xor(v, 4, 16));
            v = fmaxf(v, __shfl_xor(v, 8, 16));
            if (a == 0) rowmax2[64 * wr + 16 * rf + 4 * g + r][wc] = v;
        }
    __syncthreads();

    // ---- P' = exp(s - m_t) fp16 + per-row partial sums ----
#pragma unroll
    for (int rf = 0; rf < 4; ++rf)
#pragma unroll
        for (int r = 0; r < 4; ++r) {
            const int lrow = 64 * wr + 16 * rf + 4 * g + r;
            const float mt = fmaxf(rowmax2[lrow][0], rowmax2[lrow][1]);
            const size_t rbase = (size_t)(row0 + lrow) * NN + col0 + 64 * wc + a;
            float ps = 0.f;
#pragma unroll
            for (int cf = 0; cf < 4; ++cf) {
                const float p = __expf(acc[rf][cf][r] - mt);
                ps += p;
                Pmat[rbase + 16 * cf] = (_Float16)p;
            }
            ps += __shfl_xor(ps, 1, 16);
            ps += __shfl_xor(ps, 2, 16);
            ps += __shfl_xor(ps, 4, 16);
            ps += __shfl_xor(ps, 8, 16);
            if (a == 0) rowsum2[lrow][wc] = ps;
        }
    __syncthreads();
    if (tid < 128) {
        m_t[(size_t)blockIdx.y * NN + row0 + tid] = fmaxf(rowmax2[tid][0], rowmax2[tid][1]);
        s_t[(size_t)blockIdx.y * NN + row0 + tid] = (_Float16)(rowsum2[tid][0] + rowsum2[tid][1]);
    }
}

// ---------------- stats: m=max_t m_t; sc_t=e^{m_t-m} (f16); l=sum sc_t*s_t ----------------
__global__ __launch_bounds__(256)
void stats_kernel(const float* __restrict__ m_t, const _Float16* __restrict__ s_t,
                  _Float16* __restrict__ sc_t, float* __restrict__ l_row) {
    const int r = blockIdx.x * 256 + threadIdx.x;
    float m = -3.0e38f;
#pragma unroll 4
    for (int kt = 0; kt < NKT; ++kt) m = fmaxf(m, m_t[(size_t)kt * NN + r]);
    float l = 0.f;
#pragma unroll 4
    for (int kt = 0; kt < NKT; ++kt) {
        const float e = __expf(m_t[(size_t)kt * NN + r] - m);
        sc_t[(size_t)kt * NN + r] = (_Float16)e;
        l += e * (float)s_t[(size_t)kt * NN + r];
    }
    l_row[r] = l;
}

// ---------------- GEMM2: O = (sc*P')*F / l  -- counted-vmcnt 3-buffer pipeline ----------------
// 256 thr = 4 waves, tile 128x64, wave 64x32 (acc 4x2), BK=32, 384 K-steps.
// 3 buffers, 3 gll16/thread/stage, 36 KB LDS -> grid-limited 3 blocks/CU (same as r11).
// SAFE-INVARIANT waits: PHASE(3) = "everything except the newest stage retired" --
// correct every iteration regardless of interleaved sc pend loads (FIFO retires oldest
// first); final iteration PHASE(0). No per-step vmcnt(0) drains.
__global__ __launch_bounds__(256)
void gemm2_scale(const _Float16* __restrict__ Pmat, const _Float16* __restrict__ featT,
                 const _Float16* __restrict__ sc_t, const float* __restrict__ l_row,
                 float* __restrict__ out) {
    __shared__ alignas(16) _Float16 As[3][128 * 32];   // 24 KB  P' tiles
    __shared__ alignas(16) _Float16 Bs[3][64 * 32];    // 12 KB  V^T tiles

    const int tid = threadIdx.x, lane = tid & 63, wid = tid >> 6;
    const int g = lane >> 4, a = lane & 15;
    const int wr = wid >> 1, wc = wid & 1;
    const int row0 = blockIdx.x * 128, col0 = blockIdx.y * 64;

    f32x4 acc[4][2];
#pragma unroll
    for (int i = 0; i < 4; ++i) { acc[i][0] = f32x4{0.f,0.f,0.f,0.f}; acc[i][1] = f32x4{0.f,0.f,0.f,0.f}; }

    const int lr = lane >> 2;
    const int li = (lane & 3) * 8;
    const size_t scbase = row0 + 64 * wr + a;

    auto stage = [&](int buf, int t) {
#pragma unroll
        for (int c = 0; c < 2; ++c) {
            const int ch = wid * 2 + c;  // 0..7
            gll16(Pmat + (size_t)(row0 + ch * 16 + lr) * NN + t * 32 + li, &As[buf][ch * 512]);
        }
        gll16(featT + (size_t)(col0 + wid * 16 + lr) * NN + t * 32 + li, &Bs[buf][wid * 512]);
    };

    // sc register double-buffer (compiler manages the register-dest waits)
    _Float16 pend[4], sc[4];
#pragma unroll
    for (int rf = 0; rf < 4; ++rf) pend[rf] = sc_t[scbase + 16 * rf];

    stage(0, 0);
    stage(1, 1);          // outstanding: 6
    for (int kt = 0; kt < NKT; ++kt) {
#pragma unroll
        for (int tt = 0; tt < 4; ++tt) {
            const int t = kt * 4 + tt;
            if (kt == NKT - 1 && tt == 3) PHASE(0);
            else                          PHASE(3);
            if (tt == 0) {
#pragma unroll
                for (int rf = 0; rf < 4; ++rf) sc[rf] = pend[rf];
                if (kt + 1 < NKT) {
#pragma unroll
                    for (int rf = 0; rf < 4; ++rf)
                        pend[rf] = sc_t[(size_t)(kt + 1) * NN + scbase + 16 * rf];
                }
            }
            const int cb = t % 3;
            half8 af[4], bf[2];
#pragma unroll
            for (int rf = 0; rf < 4; ++rf) {
                af[rf] = *reinterpret_cast<const half8*>(&As[cb][(64 * wr + 16 * rf + a) * 32 + 8 * g]);
                af[rf] = af[rf] * sc[rf];
            }
#pragma unroll
            for (int cf = 0; cf < 2; ++cf)
                bf[cf] = *reinterpret_cast<const half8*>(&Bs[cb][(32 * wc + 16 * cf + a) * 32 + 8 * g]);
#pragma unroll
            for (int rf = 0; rf < 4; ++rf)
#pragma unroll
                for (int cf = 0; cf < 2; ++cf)
                    acc[rf][cf] = __builtin_amdgcn_mfma_f32_16x16x32_f16(af[rf], bf[cf], acc[rf][cf], 0, 0, 0);
            if (t + 2 < 4 * NKT) stage((t + 2) % 3, t + 2);
        }
    }

    // ---- epilogue: / l ----
#pragma unroll
    for (int rf = 0; rf < 4; ++rf)
#pragma unroll
        for (int r = 0; r < 4; ++r) {
            const int grow = row0 + 64 * wr + 16 * rf + 4 * g + r;
            const float il = 1.0f / l_row[grow];
#pragma unroll
            for (int cf = 0; cf < 2; ++cf) {
                const int gcol = col0 + 32 * wc + 16 * cf + a;
                out[(size_t)grow * FF + gcol] = acc[rf][cf][r] * il;
            }
        }
}

// =====================================================================
// Fallback: round-1 fused flash kernel (verified, 1355 us)
// =====================================================================
constexpr int BM_ = 64;
constexpr int BN_ = 64;
constexpr int KV_STRIDE = 520;

template<bool RH>
__global__ __launch_bounds__(512, 2)
void attn_flash(const float* __restrict__ featf, const _Float16* __restrict__ feath,
                const int* __restrict__ Amat, float* __restrict__ out) {
    __shared__ alignas(16) _Float16 kv[BN_ * KV_STRIDE];
    __shared__ alignas(16) _Float16 pbuf[BM_][72];
    __shared__ alignas(16) float pmax[BM_][2];
    __shared__ alignas(16) float psum[BM_][2];
    __shared__ alignas(16) float m_s[BM_];
    __shared__ alignas(16) float l_s[BM_];
    __shared__ alignas(16) float rscale[BM_];

    const int tid  = threadIdx.x;
    const int lane = tid & 63;
    const int wid  = tid >> 6;
    const int g    = lane >> 4;
    const int a    = lane & 15;
    const int rg   = wid >> 1;
    const int ch   = wid & 1;
    const int qrow0 = blockIdx.x * BM_;

    half8 qf[16];
    {
        const int qr = qrow0 + 16 * rg + a;
#pragma unroll
        for (int ks = 0; ks < 16; ++ks) {
            const int f0 = 32 * ks + 8 * g;
            if constexpr (RH) {
                qf[ks] = *reinterpret_cast<const half8*>(feath + (size_t)qr * FF + f0);
            } else {
                const float* sp = featf + (size_t)qr * FF + f0;
                float4 x = *reinterpret_cast<const float4*>(sp);
                float4 y = *reinterpret_cast<const float4*>(sp + 4);
                half8 h;
                h[0] = (_Float16)x.x; h[1] = (_Float16)x.y; h[2] = (_Float16)x.z; h[3] = (_Float16)x.w;
                h[4] = (_Float16)y.x; h[5] = (_Float16)y.y; h[6] = (_Float16)y.z; h[7] = (_Float16)y.w;
                qf[ks] = h;
            }
        }
    }

    f32x4 acc[4][4];
#pragma unroll
    for (int i = 0; i < 4; ++i)
#pragma unroll
        for (int j = 0; j < 4; ++j) acc[i][j] = f32x4{0.f, 0.f, 0.f, 0.f};

    if (tid < BM_) { m_s[tid] = -INFINITY; l_s[tid] = 0.f; }
    __syncthreads();

    for (int kt = 0; kt < NN / BN_; ++kt) {
        const int key0 = kt * BN_;
#pragma unroll
        for (int i = 0; i < 8; ++i) {
            const int flat8 = tid + i * 512;
            const int key   = flat8 >> 6;
            const int b     = flat8 & 63;
            const int slot  = (b + (key >> 3)) & 63;
            _Float16* dst = &kv[key * KV_STRIDE + slot * 8];
            if constexpr (RH) {
                *reinterpret_cast<half8*>(dst) =
                    *reinterpret_cast<const half8*>(feath + (size_t)(key0 + key) * FF + b * 8);
            } else {
                const float* sp = featf + (size_t)(key0 + key) * FF + b * 8;
                float4 x = *reinterpret_cast<const float4*>(sp);
                float4 y = *reinterpret_cast<const float4*>(sp + 4);
                half8 h;
                h[0] = (_Float16)x.x; h[1] = (_Float16)x.y; h[2] = (_Float16)x.z; h[3] = (_Float16)x.w;
                h[4] = (_Float16)y.x; h[5] = (_Float16)y.y; h[6] = (_Float16)y.z; h[7] = (_Float16)y.w;
                *reinterpret_cast<half8*>(dst) = h;
            }
        }

        int am[2][4];
#pragma unroll
        for (int fc = 0; fc < 2; ++fc)
#pragma unroll
            for (int r = 0; r < 4; ++r) {
                const int arow = qrow0 + 16 * rg + 4 * g + r;
                const int acol = key0 + 32 * ch + 16 * fc + a;
                am[fc][r] = Amat[(size_t)arow * NN + acol];
            }
        __syncthreads();

        f32x4 s0{0.f, 0.f, 0.f, 0.f}, s1{0.f, 0.f, 0.f, 0.f};
        const int bk0 = 32 * ch + a;
        const int bk1 = bk0 + 16;
        const int kb0 = bk0 >> 3;
        const int kb1 = bk1 >> 3;
        const _Float16* kr0 = &kv[bk0 * KV_STRIDE];
        const _Float16* kr1 = &kv[bk1 * KV_STRIDE];
#pragma unroll
        for (int ks = 0; ks < 16; ++ks) {
            const int b = 4 * ks + g;
            const half8 bf0 = *reinterpret_cast<const half8*>(kr0 + (((b + kb0) & 63) << 3));
            const half8 bf1 = *reinterpret_cast<const half8*>(kr1 + (((b + kb1) & 63) << 3));
            s0 = __builtin_amdgcn_mfma_f32_16x16x32_f16(qf[ks], bf0, s0, 0, 0, 0);
            s1 = __builtin_amdgcn_mfma_f32_16x16x32_f16(qf[ks], bf1, s1, 0, 0, 0);
        }

        float sv[2][4];
#pragma unroll
        for (int r = 0; r < 4; ++r) {
            sv[0][r] = (am[0][r] > 0) ? s0[r] : MASK_NEG;
            sv[1][r] = (am[1][r] > 0) ? s1[r] : MASK_NEG;
        }
#pragma unroll
        for (int r = 0; r < 4; ++r) {
            float v = fmaxf(sv[0][r], sv[1][r]);
            v = fmaxf(v, __shfl_xor(v, 1, 16));
            v = fmaxf(v, __shfl_xor(v, 2, 16));
            v = fmaxf(v, __shfl_xor(v, 4, 16));
            v = fmaxf(v, __shfl_xor(v, 8, 16));
            if (a == 0) pmax[16 * rg + 4 * g + r][ch] = v;
        }
        __syncthreads();

#pragma unroll
        for (int r = 0; r < 4; ++r) {
            const int row = 16 * rg + 4 * g + r;
            const float mo = m_s[row];
            const float mn = fmaxf(mo, fmaxf(pmax[row][0], pmax[row][1]));
            const float p0 = __expf(sv[0][r] - mn);
            const float p1 = __expf(sv[1][r] - mn);
            pbuf[row][32 * ch + a]      = (_Float16)p0;
            pbuf[row][32 * ch + 16 + a] = (_Float16)p1;
            float ssum = p0 + p1;
            ssum += __shfl_xor(ssum, 1, 16);
            ssum += __shfl_xor(ssum, 2, 16);
            ssum += __shfl_xor(ssum, 4, 16);
            ssum += __shfl_xor(ssum, 8, 16);
            if (a == 0) psum[row][ch] = ssum;
        }
        __syncthreads();

        if (tid < BM_) {
            const float mo = m_s[tid];
            const float mn = fmaxf(mo, fmaxf(pmax[tid][0], pmax[tid][1]));
            const float sc = __expf(mo - mn);
            l_s[tid] = l_s[tid] * sc + psum[tid][0] + psum[tid][1];
            m_s[tid] = mn;
            rscale[tid] = sc;
        }
        __syncthreads();

#pragma unroll
        for (int rf = 0; rf < 4; ++rf) {
            const float4 scv = *reinterpret_cast<const float4*>(&rscale[16 * rf + 4 * g]);
#pragma unroll
            for (int cf = 0; cf < 4; ++cf) {
                acc[rf][cf][0] *= scv.x; acc[rf][cf][1] *= scv.y;
                acc[rf][cf][2] *= scv.z; acc[rf][cf][3] *= scv.w;
            }
        }
#pragma unroll
        for (int kk = 0; kk < 2; ++kk) {
            half8 af[4];
#pragma unroll
            for (int rf = 0; rf < 4; ++rf)
                af[rf] = *reinterpret_cast<const half8*>(&pbuf[16 * rf + a][32 * kk + 8 * g]);
            const int keybase = 32 * kk + 8 * g;
#pragma unroll
            for (int cf = 0; cf < 4; ++cf) {
                const int col  = 64 * wid + 16 * cf + a;
                const int slot = (((col >> 3) + 4 * kk + g) & 63);
                const _Float16* vb = &kv[(size_t)keybase * KV_STRIDE + (slot << 3) + (col & 7)];
                half8 bf;
#pragma unroll
                for (int j = 0; j < 8; ++j)
                    bf[j] = vb[j * KV_STRIDE];
#pragma unroll
                for (int rf = 0; rf < 4; ++rf)
                    acc[rf][cf] = __builtin_amdgcn_mfma_f32_16x16x32_f16(af[rf], bf, acc[rf][cf], 0, 0, 0);
            }
        }
        __syncthreads();
    }

#pragma unroll
    for (int rf = 0; rf < 4; ++rf) {
        const float4 lv = *reinterpret_cast<const float4*>(&l_s[16 * rf + 4 * g]);
        const float inv[4] = {1.f / lv.x, 1.f / lv.y, 1.f / lv.z, 1.f / lv.w};
#pragma unroll
        for (int cf = 0; cf < 4; ++cf) {
            const int col = 64 * wid + 16 * cf + a;
#pragma unroll
            for (int r = 0; r < 4; ++r) {
                out[(size_t)(qrow0 + 16 * rf + 4 * g + r) * FF + col] = acc[rf][cf][r] * inv[r];
            }
        }
    }
}

extern "C" void kernel_launch(void* const* d_in, const int* in_sizes, int n_in,
                              void* d_out, int out_size, void* d_ws, size_t ws_size,
                              hipStream_t stream) {
    const float* features = (const float*)d_in[0];
    const int*   Amat     = (const int*)d_in[1];
    float*       out      = (float*)d_out;

    // ws layout (fast path, 319.4 MB). Abits + m_t live in d_out scratch (23.6 MB),
    // consumed by gemm1/stats before gemm2 overwrites d_out. Sequential stream.
    const size_t P_bytes   = (size_t)NN * NN * 2;         // 301,989,888
    const size_t f16_bytes = (size_t)NN * FF * 2;         // 12,582,912
    const size_t sct_bytes = (size_t)NKT * NN * 2;        // 2,359,296
    const size_t st_bytes  = (size_t)NKT * NN * 2;        // 2,359,296
    const size_t l_bytes   = (size_t)NN * 4;              // 49,152
    const size_t total     = P_bytes + 2 * f16_bytes + sct_bytes + st_bytes + l_bytes;

    if (ws_size >= total) {
        char* w = (char*)d_ws;
        _Float16* Pmat  = (_Float16*)w;   w += P_bytes;
        _Float16* feath = (_Float16*)w;   w += f16_bytes;
        _Float16* featT = (_Float16*)w;   w += f16_bytes;
        _Float16* sc_t  = (_Float16*)w;   w += sct_bytes;
        _Float16* s_t   = (_Float16*)w;   w += st_bytes;
        float*    l_row = (float*)w;

        uint32_t* Abits = (uint32_t*)d_out;                                    // 18.87 MB
        float*    m_t   = (float*)((char*)d_out + (size_t)NN * NWORDS * 4);    //  4.72 MB

        prepass_fused<<<CMP_BLOCKS + PREP_BLOCKS, 256, 0, stream>>>(Amat, Abits, features, feath, featT);
        gemm1_exp<<<dim3(NN / 128, NN / 128), 256, 0, stream>>>(feath, Abits, Pmat, m_t, s_t);
        stats_kernel<<<NN / 256, 256, 0, stream>>>(m_t, s_t, sc_t, l_row);
        gemm2_scale<<<dim3(NN / 128, FF / 64), 256, 0, stream>>>(Pmat, featT, sc_t, l_row, out);
    } else if (ws_size >= f16_bytes) {
        _Float16* feath = (_Float16*)d_ws;
        cvt_feat_kernel<<<(NN * FF) / (256 * 8), 256, 0, stream>>>(features, feath);
        attn_flash<true><<<NN / BM_, 512, 0, stream>>>(features, feath, Amat, out);
    } else {
        attn_flash<false><<<NN / BM_, 512, 0, stream>>>(features, nullptr, Amat, out);
    }
}

// Round 14
// 742.309 us; speedup vs baseline: 1.0414x; 1.0414x over previous
//
#include <hip/hip_runtime.h>
#include <cstddef>
#include <cstdint>

#define NN 12288
#define FF 512
#define NWORDS (NN / 32)   // 384 mask words per row
#define NKT (NN / 128)     // 96 key tiles
#define CMP_BLOCKS ((NN * NWORDS) / 256)    // 18432 compress blocks
#define PREP_BLOCKS ((NN / 32) * (FF / 32)) // 6144 prep blocks

using half8 = __attribute__((ext_vector_type(8))) _Float16;
using half4 = __attribute__((ext_vector_type(4))) _Float16;
using f32x4 = __attribute__((ext_vector_type(4))) float;

constexpr float MASK_NEG = -1e9f;  // Keras additive mask constant

// ---- async global->LDS 16B helper (wave-uniform LDS base; HW adds lane*16;
//      the GLOBAL source address is per-lane) ----
__device__ __forceinline__ void gll16(const void* g, void* l) {
    __builtin_amdgcn_global_load_lds((const __attribute__((address_space(1))) void*)g,
                                     (__attribute__((address_space(3))) void*)l, 16, 0, 0);
}

// counted-vmcnt phase sync (r8-verified): wait until <=N VMEM outstanding,
// barrier, pin following ds_reads below the barrier.
#define PHASE(N)                                                        \
    do {                                                                \
        asm volatile("s_waitcnt vmcnt(" #N ")" ::: "memory");           \
        __builtin_amdgcn_s_barrier();                                   \
        __builtin_amdgcn_sched_barrier(0);                              \
    } while (0)

// ---------------- fused prepass: A->bitmask  +  feath/featT (role-split) ----------------
// Blocks [0, CMP_BLOCKS): compress 604 MB A -> 18.9 MB bitmask (pure BW).
// Blocks [CMP_BLOCKS, +PREP_BLOCKS): fp32->fp16 row copy + 32x32 transpose.
// prep's 50 MB rides in compress's bandwidth shadow -> ~one A-read of wall time.
__global__ __launch_bounds__(256)
void prepass_fused(const int* __restrict__ Amat, uint32_t* __restrict__ Abits,
                   const float* __restrict__ in, _Float16* __restrict__ feath,
                   _Float16* __restrict__ featT) {
    const int bid = blockIdx.x;
    if (bid < CMP_BLOCKS) {
        const size_t W = (size_t)bid * 256 + threadIdx.x;  // word index
        const int4* p = reinterpret_cast<const int4*>(Amat + W * 32);
        uint32_t b = 0;
#pragma unroll
        for (int q = 0; q < 8; ++q) {
            const int4 v = p[q];
            b |= (uint32_t)(v.x > 0) << (4 * q + 0);
            b |= (uint32_t)(v.y > 0) << (4 * q + 1);
            b |= (uint32_t)(v.z > 0) << (4 * q + 2);
            b |= (uint32_t)(v.w > 0) << (4 * q + 3);
        }
        Abits[W] = b;
    } else {
        __shared__ float tile[32][33];
        const int b2 = bid - CMP_BLOCKS;
        const int bi = b2 % (NN / 32);          // n-tile (384)
        const int bj = b2 / (NN / 32);          // f-tile (16)
        const int r  = threadIdx.x >> 3;
        const int c4 = (threadIdx.x & 7) << 2;
        float4 v = *reinterpret_cast<const float4*>(in + (size_t)(bi * 32 + r) * FF + bj * 32 + c4);
        tile[r][c4 + 0] = v.x; tile[r][c4 + 1] = v.y; tile[r][c4 + 2] = v.z; tile[r][c4 + 3] = v.w;
        half4 hr;
        hr[0] = (_Float16)v.x; hr[1] = (_Float16)v.y; hr[2] = (_Float16)v.z; hr[3] = (_Float16)v.w;
        *reinterpret_cast<half4*>(feath + (size_t)(bi * 32 + r) * FF + bj * 32 + c4) = hr;
        __syncthreads();   // uniform per block (whole block takes this branch)
        half4 h;
#pragma unroll
        for (int k = 0; k < 4; ++k) h[k] = (_Float16)tile[c4 + k][r];
        *reinterpret_cast<half4*>(featT + (size_t)(bj * 32 + r) * NN + bi * 32 + c4) = h;
    }
}

// ---------------- prepass (fallback only): features fp32 -> fp16 row-major ----------------
__global__ void cvt_feat_kernel(const float* __restrict__ in, _Float16* __restrict__ out) {
    const size_t i = ((size_t)blockIdx.x * blockDim.x + threadIdx.x) * 8;
    float4 x = *reinterpret_cast<const float4*>(in + i);
    float4 y = *reinterpret_cast<const float4*>(in + i + 4);
    half8 h;
    h[0] = (_Float16)x.x; h[1] = (_Float16)x.y; h[2] = (_Float16)x.z; h[3] = (_Float16)x.w;
    h[4] = (_Float16)y.x; h[5] = (_Float16)y.y; h[6] = (_Float16)y.z; h[7] = (_Float16)y.w;
    *reinterpret_cast<half8*>(out + i) = h;
}

// ---------------- GEMM1: S=F*F^T, bit-mask epilogue, rowmax, P'=exp(s-m_t), rowsum ----------------
// r12-verbatim (counted PHASE pipeline + swizzle; measured ~334 us).
__global__ __launch_bounds__(256)
void gemm1_exp(const _Float16* __restrict__ feath, const uint32_t* __restrict__ Abits,
               _Float16* __restrict__ Pmat, float* __restrict__ m_t, _Float16* __restrict__ s_t) {
    __shared__ alignas(16) _Float16 As[3][128 * 32];
    __shared__ alignas(16) _Float16 Bs[3][128 * 32];
    __shared__ alignas(16) float rowmax2[128][2];
    __shared__ alignas(16) float rowsum2[128][2];

    const int tid = threadIdx.x, lane = tid & 63, wid = tid >> 6;
    const int g = lane >> 4, a = lane & 15;
    const int wr = wid >> 1, wc = wid & 1;
    const int row0 = blockIdx.x * 128, col0 = blockIdx.y * 128;

    f32x4 acc[4][4];
#pragma unroll
    for (int i = 0; i < 4; ++i)
#pragma unroll
        for (int j = 0; j < 4; ++j) acc[i][j] = f32x4{0.f, 0.f, 0.f, 0.f};

    const int lr  = lane >> 2;                    // 0..15 row within 16-row chunk
    const int sl  = lane & 3;                     // physical 16B slot this lane fills
    const int lsw = (sl ^ ((lr >> 1) & 3)) * 8;   // pre-swizzled logical f16 offset
    const int rk  = (a >> 1) & 3;                 // read-side XOR key (row>>1)&3

    auto stage = [&](int buf, int t) {
#pragma unroll
        for (int c = 0; c < 2; ++c) {
            const int ch = wid * 2 + c;  // 0..7
            gll16(feath + (size_t)(row0 + ch * 16 + lr) * FF + t * 32 + lsw, &As[buf][ch * 512]);
            gll16(feath + (size_t)(col0 + ch * 16 + lr) * FF + t * 32 + lsw, &Bs[buf][ch * 512]);
        }
    };

    stage(0, 0);
    stage(1, 1);          // outstanding: 8
#pragma unroll
    for (int t = 0; t < 16; ++t) {
        if (t < 15) PHASE(4);   // retire buffer t's 4 loads; keep t+1 in flight
        else        PHASE(0);
        const int cb = t % 3;
        half8 af[4], bf[4];
#pragma unroll
        for (int rf = 0; rf < 4; ++rf)
            af[rf] = *reinterpret_cast<const half8*>(&As[cb][(64 * wr + 16 * rf + a) * 32 + ((g ^ rk) << 3)]);
#pragma unroll
        for (int cf = 0; cf < 4; ++cf)
            bf[cf] = *reinterpret_cast<const half8*>(&Bs[cb][(64 * wc + 16 * cf + a) * 32 + ((g ^ rk) << 3)]);
#pragma unroll
        for (int rf = 0; rf < 4; ++rf)
#pragma unroll
            for (int cf = 0; cf < 4; ++cf)
                acc[rf][cf] = __builtin_amdgcn_mfma_f32_16x16x32_f16(af[rf], bf[cf], acc[rf][cf], 0, 0, 0);
        if (t + 2 < 16) stage((t + 2) % 3, t + 2);
    }

    // ---- mask from bit-matrix: 16 broadcast uint2 loads (L3-resident 19 MB) ----
    const int cw0 = (col0 + 64 * wc) >> 5;   // even word index -> 8B aligned
    uint2 am[4][4];
#pragma unroll
    for (int rf = 0; rf < 4; ++rf)
#pragma unroll
        for (int r = 0; r < 4; ++r) {
            const int grow = row0 + 64 * wr + 16 * rf + 4 * g + r;
            am[rf][r] = *reinterpret_cast<const uint2*>(&Abits[(size_t)grow * NWORDS + cw0]);
        }
#pragma unroll
    for (int rf = 0; rf < 4; ++rf)
#pragma unroll
        for (int r = 0; r < 4; ++r)
#pragma unroll
            for (int cf = 0; cf < 4; ++cf) {
                const uint32_t w = (cf < 2) ? am[rf][r].x : am[rf][r].y;
                const uint32_t bit = (w >> (a + 16 * (cf & 1))) & 1u;
                acc[rf][cf][r] = bit ? acc[rf][cf][r] : MASK_NEG;
            }

    // ---- per-row tile max (16 col-lanes reduce, halves via LDS) ----
#pragma unroll
    for (int rf = 0; rf < 4; ++rf)
#pragma unroll
        for (int r = 0; r < 4; ++r) {
            float v = fmaxf(fmaxf(acc[rf][0][r], acc[rf][1][r]), fmaxf(acc[rf][2][r], acc[rf][3][r]));
            v = fmaxf(v, __shfl_xor(v, 1, 16));
            v = fmaxf(v, __shfl_xor(v, 2, 16));
            v = fmaxf(v, __shfl_xor(v, 4, 16));
            v = fmaxf(v, __shfl_xor(v, 8, 16));
            if (a == 0) rowmax2[64 * wr + 16 * rf + 4 * g + r][wc] = v;
        }
    __syncthreads();

    // ---- P' = exp(s - m_t) fp16 + per-row partial sums ----
#pragma unroll
    for (int rf = 0; rf < 4; ++rf)
#pragma unroll
        for (int r = 0; r < 4; ++r) {
            const int lrow = 64 * wr + 16 * rf + 4 * g + r;
            const float mt = fmaxf(rowmax2[lrow][0], rowmax2[lrow][1]);
            const size_t rbase = (size_t)(row0 + lrow) * NN + col0 + 64 * wc + a;
            float ps = 0.f;
#pragma unroll
            for (int cf = 0; cf < 4; ++cf) {
                const float p = __expf(acc[rf][cf][r] - mt);
                ps += p;
                Pmat[rbase + 16 * cf] = (_Float16)p;
            }
            ps += __shfl_xor(ps, 1, 16);
            ps += __shfl_xor(ps, 2, 16);
            ps += __shfl_xor(ps, 4, 16);
            ps += __shfl_xor(ps, 8, 16);
            if (a == 0) rowsum2[lrow][wc] = ps;
        }
    __syncthreads();
    if (tid < 128) {
        m_t[(size_t)blockIdx.y * NN + row0 + tid] = fmaxf(rowmax2[tid][0], rowmax2[tid][1]);
        s_t[(size_t)blockIdx.y * NN + row0 + tid] = (_Float16)(rowsum2[tid][0] + rowsum2[tid][1]);
    }
}

// ---------------- stats: m=max_t m_t; sc_t=e^{m_t-m} (f16); l=sum sc_t*s_t ----------------
__global__ __launch_bounds__(256)
void stats_kernel(const float* __restrict__ m_t, const _Float16* __restrict__ s_t,
                  _Float16* __restrict__ sc_t, float* __restrict__ l_row) {
    const int r = blockIdx.x * 256 + threadIdx.x;
    float m = -3.0e38f;
#pragma unroll 4
    for (int kt = 0; kt < NKT; ++kt) m = fmaxf(m, m_t[(size_t)kt * NN + r]);
    float l = 0.f;
#pragma unroll 4
    for (int kt = 0; kt < NKT; ++kt) {
        const float e = __expf(m_t[(size_t)kt * NN + r] - m);
        sc_t[(size_t)kt * NN + r] = (_Float16)e;
        l += e * (float)s_t[(size_t)kt * NN + r];
    }
    l_row[r] = l;
}

// ---------------- GEMM2: O = (sc*P')*F / l  (r12-verbatim: BK=64, 2-buf, XOR swizzle) ----------------
__global__ __launch_bounds__(256)
void gemm2_scale(const _Float16* __restrict__ Pmat, const _Float16* __restrict__ featT,
                 const _Float16* __restrict__ sc_t, const float* __restrict__ l_row,
                 float* __restrict__ out) {
    __shared__ alignas(16) _Float16 As[2][128 * 64];   // 32 KB  P' tiles (row stride 64)
    __shared__ alignas(16) _Float16 Bs[2][64 * 64];    // 16 KB  V^T tiles

    const int tid = threadIdx.x, lane = tid & 63, wid = tid >> 6;
    const int g = lane >> 4, a = lane & 15;
    const int wr = wid >> 1, wc = wid & 1;
    const int row0 = blockIdx.x * 128, col0 = blockIdx.y * 64;

    f32x4 acc[4][2];
#pragma unroll
    for (int i = 0; i < 4; ++i) { acc[i][0] = f32x4{0.f,0.f,0.f,0.f}; acc[i][1] = f32x4{0.f,0.f,0.f,0.f}; }

    const int l8  = lane >> 3;   // 0..7 = row-in-segment = XOR key at write
    const int sc8 = lane & 7;    // stored c8 slot
    const int xk  = a & 7;       // XOR key at read (row & 7 for all fragment rows)
    const size_t scbase = row0 + 64 * wr + a;

    auto stage = [&](int buf, int t) {
#pragma unroll
        for (int c = 0; c < 4; ++c) {
            const int seg = wid * 4 + c;                 // 0..15
            const int row = seg * 8 + l8;
            gll16(Pmat + (size_t)(row0 + row) * NN + t * 64 + ((sc8 ^ l8) << 3),
                  &As[buf][seg * 512]);
        }
#pragma unroll
        for (int c = 0; c < 2; ++c) {
            const int seg = wid * 2 + c;                 // 0..7
            const int row = seg * 8 + l8;
            gll16(featT + (size_t)(col0 + row) * NN + t * 64 + ((sc8 ^ l8) << 3),
                  &Bs[buf][seg * 512]);
        }
    };

    _Float16 pend[4], sc[4];
#pragma unroll
    for (int rf = 0; rf < 4; ++rf) pend[rf] = sc_t[scbase + 16 * rf];

    stage(0, 0);
    __syncthreads();
    int buf = 0;
    for (int t = 0; t < 192; ++t) {
        if ((t & 1) == 0) {
#pragma unroll
            for (int rf = 0; rf < 4; ++rf) sc[rf] = pend[rf];
            const int ktn = (t >> 1) + 1;
            if (ktn < NKT) {
#pragma unroll
                for (int rf = 0; rf < 4; ++rf)
                    pend[rf] = sc_t[(size_t)ktn * NN + scbase + 16 * rf];
            }
        }
        if (t + 1 < 192) stage(buf ^ 1, t + 1);
#pragma unroll
        for (int kk = 0; kk < 2; ++kk) {
            const int c8r = ((kk << 2) + g) ^ xk;        // swizzled read slot
            half8 af[4], bf[2];
#pragma unroll
            for (int rf = 0; rf < 4; ++rf) {
                const int row = 64 * wr + 16 * rf + a;
                af[rf] = *reinterpret_cast<const half8*>(&As[buf][row * 64 + (c8r << 3)]);
                af[rf] = af[rf] * sc[rf];
            }
#pragma unroll
            for (int cf = 0; cf < 2; ++cf) {
                const int row = 32 * wc + 16 * cf + a;
                bf[cf] = *reinterpret_cast<const half8*>(&Bs[buf][row * 64 + (c8r << 3)]);
            }
#pragma unroll
            for (int rf = 0; rf < 4; ++rf)
#pragma unroll
                for (int cf = 0; cf < 2; ++cf)
                    acc[rf][cf] = __builtin_amdgcn_mfma_f32_16x16x32_f16(af[rf], bf[cf], acc[rf][cf], 0, 0, 0);
        }
        __syncthreads();
        buf ^= 1;
    }

    // ---- epilogue: / l ----
#pragma unroll
    for (int rf = 0; rf < 4; ++rf)
#pragma unroll
        for (int r = 0; r < 4; ++r) {
            const int grow = row0 + 64 * wr + 16 * rf + 4 * g + r;
            const float il = 1.0f / l_row[grow];
#pragma unroll
            for (int cf = 0; cf < 2; ++cf) {
                const int gcol = col0 + 32 * wc + 16 * cf + a;
                out[(size_t)grow * FF + gcol] = acc[rf][cf][r] * il;
            }
        }
}

// =====================================================================
// Fallback: round-1 fused flash kernel (verified, 1355 us)
// =====================================================================
constexpr int BM_ = 64;
constexpr int BN_ = 64;
constexpr int KV_STRIDE = 520;

template<bool RH>
__global__ __launch_bounds__(512, 2)
void attn_flash(const float* __restrict__ featf, const _Float16* __restrict__ feath,
                const int* __restrict__ Amat, float* __restrict__ out) {
    __shared__ alignas(16) _Float16 kv[BN_ * KV_STRIDE];
    __shared__ alignas(16) _Float16 pbuf[BM_][72];
    __shared__ alignas(16) float pmax[BM_][2];
    __shared__ alignas(16) float psum[BM_][2];
    __shared__ alignas(16) float m_s[BM_];
    __shared__ alignas(16) float l_s[BM_];
    __shared__ alignas(16) float rscale[BM_];

    const int tid  = threadIdx.x;
    const int lane = tid & 63;
    const int wid  = tid >> 6;
    const int g    = lane >> 4;
    const int a    = lane & 15;
    const int rg   = wid >> 1;
    const int ch   = wid & 1;
    const int qrow0 = blockIdx.x * BM_;

    half8 qf[16];
    {
        const int qr = qrow0 + 16 * rg + a;
#pragma unroll
        for (int ks = 0; ks < 16; ++ks) {
            const int f0 = 32 * ks + 8 * g;
            if constexpr (RH) {
                qf[ks] = *reinterpret_cast<const half8*>(feath + (size_t)qr * FF + f0);
            } else {
                const float* sp = featf + (size_t)qr * FF + f0;
                float4 x = *reinterpret_cast<const float4*>(sp);
                float4 y = *reinterpret_cast<const float4*>(sp + 4);
                half8 h;
                h[0] = (_Float16)x.x; h[1] = (_Float16)x.y; h[2] = (_Float16)x.z; h[3] = (_Float16)x.w;
                h[4] = (_Float16)y.x; h[5] = (_Float16)y.y; h[6] = (_Float16)y.z; h[7] = (_Float16)y.w;
                qf[ks] = h;
            }
        }
    }

    f32x4 acc[4][4];
#pragma unroll
    for (int i = 0; i < 4; ++i)
#pragma unroll
        for (int j = 0; j < 4; ++j) acc[i][j] = f32x4{0.f, 0.f, 0.f, 0.f};

    if (tid < BM_) { m_s[tid] = -INFINITY; l_s[tid] = 0.f; }
    __syncthreads();

    for (int kt = 0; kt < NN / BN_; ++kt) {
        const int key0 = kt * BN_;
#pragma unroll
        for (int i = 0; i < 8; ++i) {
            const int flat8 = tid + i * 512;
            const int key   = flat8 >> 6;
            const int b     = flat8 & 63;
            const int slot  = (b + (key >> 3)) & 63;
            _Float16* dst = &kv[key * KV_STRIDE + slot * 8];
            if constexpr (RH) {
                *reinterpret_cast<half8*>(dst) =
                    *reinterpret_cast<const half8*>(feath + (size_t)(key0 + key) * FF + b * 8);
            } else {
                const float* sp = featf + (size_t)(key0 + key) * FF + b * 8;
                float4 x = *reinterpret_cast<const float4*>(sp);
                float4 y = *reinterpret_cast<const float4*>(sp + 4);
                half8 h;
                h[0] = (_Float16)x.x; h[1] = (_Float16)x.y; h[2] = (_Float16)x.z; h[3] = (_Float16)x.w;
                h[4] = (_Float16)y.x; h[5] = (_Float16)y.y; h[6] = (_Float16)y.z; h[7] = (_Float16)y.w;
                *reinterpret_cast<half8*>(dst) = h;
            }
        }

        int am[2][4];
#pragma unroll
        for (int fc = 0; fc < 2; ++fc)
#pragma unroll
            for (int r = 0; r < 4; ++r) {
                const int arow = qrow0 + 16 * rg + 4 * g + r;
                const int acol = key0 + 32 * ch + 16 * fc + a;
                am[fc][r] = Amat[(size_t)arow * NN + acol];
            }
        __syncthreads();

        f32x4 s0{0.f, 0.f, 0.f, 0.f}, s1{0.f, 0.f, 0.f, 0.f};
        const int bk0 = 32 * ch + a;
        const int bk1 = bk0 + 16;
        const int kb0 = bk0 >> 3;
        const int kb1 = bk1 >> 3;
        const _Float16* kr0 = &kv[bk0 * KV_STRIDE];
        const _Float16* kr1 = &kv[bk1 * KV_STRIDE];
#pragma unroll
        for (int ks = 0; ks < 16; ++ks) {
            const int b = 4 * ks + g;
            const half8 bf0 = *reinterpret_cast<const half8*>(kr0 + (((b + kb0) & 63) << 3));
            const half8 bf1 = *reinterpret_cast<const half8*>(kr1 + (((b + kb1) & 63) << 3));
            s0 = __builtin_amdgcn_mfma_f32_16x16x32_f16(qf[ks], bf0, s0, 0, 0, 0);
            s1 = __builtin_amdgcn_mfma_f32_16x16x32_f16(qf[ks], bf1, s1, 0, 0, 0);
        }

        float sv[2][4];
#pragma unroll
        for (int r = 0; r < 4; ++r) {
            sv[0][r] = (am[0][r] > 0) ? s0[r] : MASK_NEG;
            sv[1][r] = (am[1][r] > 0) ? s1[r] : MASK_NEG;
        }
#pragma unroll
        for (int r = 0; r < 4; ++r) {
            float v = fmaxf(sv[0][r], sv[1][r]);
            v = fmaxf(v, __shfl_xor(v, 1, 16));
            v = fmaxf(v, __shfl_xor(v, 2, 16));
            v = fmaxf(v, __shfl_xor(v, 4, 16));
            v = fmaxf(v, __shfl_xor(v, 8, 16));
            if (a == 0) pmax[16 * rg + 4 * g + r][ch] = v;
        }
        __syncthreads();

#pragma unroll
        for (int r = 0; r < 4; ++r) {
            const int row = 16 * rg + 4 * g + r;
            const float mo = m_s[row];
            const float mn = fmaxf(mo, fmaxf(pmax[row][0], pmax[row][1]));
            const float p0 = __expf(sv[0][r] - mn);
            const float p1 = __expf(sv[1][r] - mn);
            pbuf[row][32 * ch + a]      = (_Float16)p0;
            pbuf[row][32 * ch + 16 + a] = (_Float16)p1;
            float ssum = p0 + p1;
            ssum += __shfl_xor(ssum, 1, 16);
            ssum += __shfl_xor(ssum, 2, 16);
            ssum += __shfl_xor(ssum, 4, 16);
            ssum += __shfl_xor(ssum, 8, 16);
            if (a == 0) psum[row][ch] = ssum;
        }
        __syncthreads();

        if (tid < BM_) {
            const float mo = m_s[tid];
            const float mn = fmaxf(mo, fmaxf(pmax[tid][0], pmax[tid][1]));
            const float sc = __expf(mo - mn);
            l_s[tid] = l_s[tid] * sc + psum[tid][0] + psum[tid][1];
            m_s[tid] = mn;
            rscale[tid] = sc;
        }
        __syncthreads();

#pragma unroll
        for (int rf = 0; rf < 4; ++rf) {
            const float4 scv = *reinterpret_cast<const float4*>(&rscale[16 * rf + 4 * g]);
#pragma unroll
            for (int cf = 0; cf < 4; ++cf) {
                acc[rf][cf][0] *= scv.x; acc[rf][cf][1] *= scv.y;
                acc[rf][cf][2] *= scv.z; acc[rf][cf][3] *= scv.w;
            }
        }
#pragma unroll
        for (int kk = 0; kk < 2; ++kk) {
            half8 af[4];
#pragma unroll
            for (int rf = 0; rf < 4; ++rf)
                af[rf] = *reinterpret_cast<const half8*>(&pbuf[16 * rf + a][32 * kk + 8 * g]);
            const int keybase = 32 * kk + 8 * g;
#pragma unroll
            for (int cf = 0; cf < 4; ++cf) {
                const int col  = 64 * wid + 16 * cf + a;
                const int slot = (((col >> 3) + 4 * kk + g) & 63);
                const _Float16* vb = &kv[(size_t)keybase * KV_STRIDE + (slot << 3) + (col & 7)];
                half8 bf;
#pragma unroll
                for (int j = 0; j < 8; ++j)
                    bf[j] = vb[j * KV_STRIDE];
#pragma unroll
                for (int rf = 0; rf < 4; ++rf)
                    acc[rf][cf] = __builtin_amdgcn_mfma_f32_16x16x32_f16(af[rf], bf, acc[rf][cf], 0, 0, 0);
            }
        }
        __syncthreads();
    }

#pragma unroll
    for (int rf = 0; rf < 4; ++rf) {
        const float4 lv = *reinterpret_cast<const float4*>(&l_s[16 * rf + 4 * g]);
        const float inv[4] = {1.f / lv.x, 1.f / lv.y, 1.f / lv.z, 1.f / lv.w};
#pragma unroll
        for (int cf = 0; cf < 4; ++cf) {
            const int col = 64 * wid + 16 * cf + a;
#pragma unroll
            for (int r = 0; r < 4; ++r) {
                out[(size_t)(qrow0 + 16 * rf + 4 * g + r) * FF + col] = acc[rf][cf][r] * inv[r];
            }
        }
    }
}

extern "C" void kernel_launch(void* const* d_in, const int* in_sizes, int n_in,
                              void* d_out, int out_size, void* d_ws, size_t ws_size,
                              hipStream_t stream) {
    const float* features = (const float*)d_in[0];
    const int*   Amat     = (const int*)d_in[1];
    float*       out      = (float*)d_out;

    // ws layout (fast path, 319.4 MB). Abits + m_t live in d_out scratch (23.6 MB),
    // consumed by gemm1/stats before gemm2 overwrites d_out. Sequential stream.
    const size_t P_bytes   = (size_t)NN * NN * 2;         // 301,989,888
    const size_t f16_bytes = (size_t)NN * FF * 2;         // 12,582,912
    const size_t sct_bytes = (size_t)NKT * NN * 2;        // 2,359,296
    const size_t st_bytes  = (size_t)NKT * NN * 2;        // 2,359,296
    const size_t l_bytes   = (size_t)NN * 4;              // 49,152
    const size_t total     = P_bytes + 2 * f16_bytes + sct_bytes + st_bytes + l_bytes;

    if (ws_size >= total) {
        char* w = (char*)d_ws;
        _Float16* Pmat  = (_Float16*)w;   w += P_bytes;
        _Float16* feath = (_Float16*)w;   w += f16_bytes;
        _Float16* featT = (_Float16*)w;   w += f16_bytes;
        _Float16* sc_t  = (_Float16*)w;   w += sct_bytes;
        _Float16* s_t   = (_Float16*)w;   w += st_bytes;
        float*    l_row = (float*)w;

        uint32_t* Abits = (uint32_t*)d_out;                                    // 18.87 MB
        float*    m_t   = (float*)((char*)d_out + (size_t)NN * NWORDS * 4);    //  4.72 MB

        prepass_fused<<<CMP_BLOCKS + PREP_BLOCKS, 256, 0, stream>>>(Amat, Abits, features, feath, featT);
        gemm1_exp<<<dim3(NN / 128, NN / 128), 256, 0, stream>>>(feath, Abits, Pmat, m_t, s_t);
        stats_kernel<<<NN / 256, 256, 0, stream>>>(m_t, s_t, sc_t, l_row);
        gemm2_scale<<<dim3(NN / 128, FF / 64), 256, 0, stream>>>(Pmat, featT, sc_t, l_row, out);
    } else if (ws_size >= f16_bytes) {
        _Float16* feath = (_Float16*)d_ws;
        cvt_feat_kernel<<<(NN * FF) / (256 * 8), 256, 0, stream>>>(features, feath);
        attn_flash<true><<<NN / BM_, 512, 0, stream>>>(features, feath, Amat, out);
    } else {
        attn_flash<false><<<NN / BM_, 512, 0, stream>>>(features, nullptr, Amat, out);
    }
}

// Round 15
// 729.444 us; speedup vs baseline: 1.0597x; 1.0176x over previous
//
#include <hip/hip_runtime.h>
#include <cstddef>
#include <cstdint>

#define NN 12288
#define FF 512
#define NWORDS (NN / 32)   // 384 mask words per row
#define NKT (NN / 128)     // 96 key tiles
#define CMP_BLOCKS ((NN * NWORDS) / 256)    // 18432 compress blocks
#define PREP_BLOCKS ((NN / 32) * (FF / 32)) // 6144 prep blocks

using half8 = __attribute__((ext_vector_type(8))) _Float16;
using half4 = __attribute__((ext_vector_type(4))) _Float16;
using f32x4 = __attribute__((ext_vector_type(4))) float;

constexpr float MASK_NEG = -1e9f;  // Keras additive mask constant

// ---- async global->LDS 16B helper (wave-uniform LDS base; HW adds lane*16;
//      the GLOBAL source address is per-lane) ----
__device__ __forceinline__ void gll16(const void* g, void* l) {
    __builtin_amdgcn_global_load_lds((const __attribute__((address_space(1))) void*)g,
                                     (__attribute__((address_space(3))) void*)l, 16, 0, 0);
}

// ---------------- fused prepass: A->bitmask  +  feath/featT (role-split) ----------------
__global__ __launch_bounds__(256)
void prepass_fused(const int* __restrict__ Amat, uint32_t* __restrict__ Abits,
                   const float* __restrict__ in, _Float16* __restrict__ feath,
                   _Float16* __restrict__ featT) {
    const int bid = blockIdx.x;
    if (bid < CMP_BLOCKS) {
        const size_t W = (size_t)bid * 256 + threadIdx.x;  // word index
        const int4* p = reinterpret_cast<const int4*>(Amat + W * 32);
        uint32_t b = 0;
#pragma unroll
        for (int q = 0; q < 8; ++q) {
            const int4 v = p[q];
            b |= (uint32_t)(v.x > 0) << (4 * q + 0);
            b |= (uint32_t)(v.y > 0) << (4 * q + 1);
            b |= (uint32_t)(v.z > 0) << (4 * q + 2);
            b |= (uint32_t)(v.w > 0) << (4 * q + 3);
        }
        Abits[W] = b;
    } else {
        __shared__ float tile[32][33];
        const int b2 = bid - CMP_BLOCKS;
        const int bi = b2 % (NN / 32);          // n-tile (384)
        const int bj = b2 / (NN / 32);          // f-tile (16)
        const int r  = threadIdx.x >> 3;
        const int c4 = (threadIdx.x & 7) << 2;
        float4 v = *reinterpret_cast<const float4*>(in + (size_t)(bi * 32 + r) * FF + bj * 32 + c4);
        tile[r][c4 + 0] = v.x; tile[r][c4 + 1] = v.y; tile[r][c4 + 2] = v.z; tile[r][c4 + 3] = v.w;
        half4 hr;
        hr[0] = (_Float16)v.x; hr[1] = (_Float16)v.y; hr[2] = (_Float16)v.z; hr[3] = (_Float16)v.w;
        *reinterpret_cast<half4*>(feath + (size_t)(bi * 32 + r) * FF + bj * 32 + c4) = hr;
        __syncthreads();   // uniform per block (whole block takes this branch)
        half4 h;
#pragma unroll
        for (int k = 0; k < 4; ++k) h[k] = (_Float16)tile[c4 + k][r];
        *reinterpret_cast<half4*>(featT + (size_t)(bj * 32 + r) * NN + bi * 32 + c4) = h;
    }
}

// ---------------- prepass (fallback only): features fp32 -> fp16 row-major ----------------
__global__ void cvt_feat_kernel(const float* __restrict__ in, _Float16* __restrict__ out) {
    const size_t i = ((size_t)blockIdx.x * blockDim.x + threadIdx.x) * 8;
    float4 x = *reinterpret_cast<const float4*>(in + i);
    float4 y = *reinterpret_cast<const float4*>(in + i + 4);
    half8 h;
    h[0] = (_Float16)x.x; h[1] = (_Float16)x.y; h[2] = (_Float16)x.z; h[3] = (_Float16)x.w;
    h[4] = (_Float16)y.x; h[5] = (_Float16)y.y; h[6] = (_Float16)y.z; h[7] = (_Float16)y.w;
    *reinterpret_cast<half8*>(out + i) = h;
}

// ---------------- GEMM1: S=F*F^T, bit-mask epilogue, rowmax, P'=exp(s-m_t), rowsum ----------------
// THIS ROUND: BK 32->64 (8 K-steps, 32 MFMA/step), porting gemm2's r11-verified
// 2-buf stage-early structure + XOR swizzle (linear LDS dest, pre-swizzled global
// source slot^=row&7, matching read XOR). LDS 66.5 KB -> 2 blocks/CU (= measured
// residency of the old config, so no occupancy loss; barrier count halves).
__global__ __launch_bounds__(256)
void gemm1_exp(const _Float16* __restrict__ feath, const uint32_t* __restrict__ Abits,
               _Float16* __restrict__ Pmat, float* __restrict__ m_t, _Float16* __restrict__ s_t) {
    __shared__ alignas(16) _Float16 As[2][128 * 64];   // 32 KB
    __shared__ alignas(16) _Float16 Bs[2][128 * 64];   // 32 KB
    __shared__ alignas(16) float rowmax2[128][2];
    __shared__ alignas(16) float rowsum2[128][2];

    const int tid = threadIdx.x, lane = tid & 63, wid = tid >> 6;
    const int g = lane >> 4, a = lane & 15;
    const int wr = wid >> 1, wc = wid & 1;
    const int row0 = blockIdx.x * 128, col0 = blockIdx.y * 128;

    f32x4 acc[4][4];
#pragma unroll
    for (int i = 0; i < 4; ++i)
#pragma unroll
        for (int j = 0; j < 4; ++j) acc[i][j] = f32x4{0.f, 0.f, 0.f, 0.f};

    const int l8  = lane >> 3;   // 0..7 = row-in-segment = XOR key at write
    const int sc8 = lane & 7;    // stored 16B slot
    const int xk  = a & 7;       // read-side XOR key (row & 7 for all fragment rows)

    // stage K-columns [t*64, t*64+64) of 128 rows for As and Bs:
    // 16 segments of 8 rows each; lane fills (row = seg*8+l8, stored slot sc8),
    // sourcing logical slot sc8^l8 -> read back with slot ^ (row&7).
    auto stage = [&](int buf, int t) {
#pragma unroll
        for (int c = 0; c < 4; ++c) {
            const int seg = wid * 4 + c;                 // 0..15
            const int row = seg * 8 + l8;
            gll16(feath + (size_t)(row0 + row) * FF + t * 64 + ((sc8 ^ l8) << 3),
                  &As[buf][seg * 512]);
            gll16(feath + (size_t)(col0 + row) * FF + t * 64 + ((sc8 ^ l8) << 3),
                  &Bs[buf][seg * 512]);
        }
    };

    stage(0, 0);
    __syncthreads();
    int buf = 0;
#pragma unroll
    for (int t = 0; t < 8; ++t) {
        if (t + 1 < 8) stage(buf ^ 1, t + 1);
#pragma unroll
        for (int kk = 0; kk < 2; ++kk) {
            const int c8r = ((kk << 2) + g) ^ xk;        // swizzled read slot
            half8 af[4], bf[4];
#pragma unroll
            for (int rf = 0; rf < 4; ++rf) {
                const int row = 64 * wr + 16 * rf + a;
                af[rf] = *reinterpret_cast<const half8*>(&As[buf][row * 64 + (c8r << 3)]);
            }
#pragma unroll
            for (int cf = 0; cf < 4; ++cf) {
                const int row = 64 * wc + 16 * cf + a;
                bf[cf] = *reinterpret_cast<const half8*>(&Bs[buf][row * 64 + (c8r << 3)]);
            }
#pragma unroll
            for (int rf = 0; rf < 4; ++rf)
#pragma unroll
                for (int cf = 0; cf < 4; ++cf)
                    acc[rf][cf] = __builtin_amdgcn_mfma_f32_16x16x32_f16(af[rf], bf[cf], acc[rf][cf], 0, 0, 0);
        }
        __syncthreads();
        buf ^= 1;
    }

    // ---- mask from bit-matrix: 16 broadcast uint2 loads (L3-resident 19 MB) ----
    const int cw0 = (col0 + 64 * wc) >> 5;   // even word index -> 8B aligned
    uint2 am[4][4];
#pragma unroll
    for (int rf = 0; rf < 4; ++rf)
#pragma unroll
        for (int r = 0; r < 4; ++r) {
            const int grow = row0 + 64 * wr + 16 * rf + 4 * g + r;
            am[rf][r] = *reinterpret_cast<const uint2*>(&Abits[(size_t)grow * NWORDS + cw0]);
        }
#pragma unroll
    for (int rf = 0; rf < 4; ++rf)
#pragma unroll
        for (int r = 0; r < 4; ++r)
#pragma unroll
            for (int cf = 0; cf < 4; ++cf) {
                const uint32_t w = (cf < 2) ? am[rf][r].x : am[rf][r].y;
                const uint32_t bit = (w >> (a + 16 * (cf & 1))) & 1u;
                acc[rf][cf][r] = bit ? acc[rf][cf][r] : MASK_NEG;
            }

    // ---- per-row tile max (16 col-lanes reduce, halves via LDS) ----
#pragma unroll
    for (int rf = 0; rf < 4; ++rf)
#pragma unroll
        for (int r = 0; r < 4; ++r) {
            float v = fmaxf(fmaxf(acc[rf][0][r], acc[rf][1][r]), fmaxf(acc[rf][2][r], acc[rf][3][r]));
            v = fmaxf(v, __shfl_xor(v, 1, 16));
            v = fmaxf(v, __shfl_xor(v, 2, 16));
            v = fmaxf(v, __shfl_xor(v, 4, 16));
            v = fmaxf(v, __shfl_xor(v, 8, 16));
            if (a == 0) rowmax2[64 * wr + 16 * rf + 4 * g + r][wc] = v;
        }
    __syncthreads();

    // ---- P' = exp(s - m_t) fp16 + per-row partial sums ----
#pragma unroll
    for (int rf = 0; rf < 4; ++rf)
#pragma unroll
        for (int r = 0; r < 4; ++r) {
            const int lrow = 64 * wr + 16 * rf + 4 * g + r;
            const float mt = fmaxf(rowmax2[lrow][0], rowmax2[lrow][1]);
            const size_t rbase = (size_t)(row0 + lrow) * NN + col0 + 64 * wc + a;
            float ps = 0.f;
#pragma unroll
            for (int cf = 0; cf < 4; ++cf) {
                const float p = __expf(acc[rf][cf][r] - mt);
                ps += p;
                Pmat[rbase + 16 * cf] = (_Float16)p;
            }
            ps += __shfl_xor(ps, 1, 16);
            ps += __shfl_xor(ps, 2, 16);
            ps += __shfl_xor(ps, 4, 16);
            ps += __shfl_xor(ps, 8, 16);
            if (a == 0) rowsum2[lrow][wc] = ps;
        }
    __syncthreads();
    if (tid < 128) {
        m_t[(size_t)blockIdx.y * NN + row0 + tid] = fmaxf(rowmax2[tid][0], rowmax2[tid][1]);
        s_t[(size_t)blockIdx.y * NN + row0 + tid] = (_Float16)(rowsum2[tid][0] + rowsum2[tid][1]);
    }
}

// ---------------- stats: m=max_t m_t; sc_t=e^{m_t-m} (f16); l=sum sc_t*s_t ----------------
__global__ __launch_bounds__(256)
void stats_kernel(const float* __restrict__ m_t, const _Float16* __restrict__ s_t,
                  _Float16* __restrict__ sc_t, float* __restrict__ l_row) {
    const int r = blockIdx.x * 256 + threadIdx.x;
    float m = -3.0e38f;
#pragma unroll 4
    for (int kt = 0; kt < NKT; ++kt) m = fmaxf(m, m_t[(size_t)kt * NN + r]);
    float l = 0.f;
#pragma unroll 4
    for (int kt = 0; kt < NKT; ++kt) {
        const float e = __expf(m_t[(size_t)kt * NN + r] - m);
        sc_t[(size_t)kt * NN + r] = (_Float16)e;
        l += e * (float)s_t[(size_t)kt * NN + r];
    }
    l_row[r] = l;
}

// ---------------- GEMM2: O = (sc*P')*F / l  (r12-verbatim: BK=64, 2-buf, XOR swizzle) ----------------
__global__ __launch_bounds__(256)
void gemm2_scale(const _Float16* __restrict__ Pmat, const _Float16* __restrict__ featT,
                 const _Float16* __restrict__ sc_t, const float* __restrict__ l_row,
                 float* __restrict__ out) {
    __shared__ alignas(16) _Float16 As[2][128 * 64];   // 32 KB  P' tiles (row stride 64)
    __shared__ alignas(16) _Float16 Bs[2][64 * 64];    // 16 KB  V^T tiles

    const int tid = threadIdx.x, lane = tid & 63, wid = tid >> 6;
    const int g = lane >> 4, a = lane & 15;
    const int wr = wid >> 1, wc = wid & 1;
    const int row0 = blockIdx.x * 128, col0 = blockIdx.y * 64;

    f32x4 acc[4][2];
#pragma unroll
    for (int i = 0; i < 4; ++i) { acc[i][0] = f32x4{0.f,0.f,0.f,0.f}; acc[i][1] = f32x4{0.f,0.f,0.f,0.f}; }

    const int l8  = lane >> 3;   // 0..7 = row-in-segment = XOR key at write
    const int sc8 = lane & 7;    // stored c8 slot
    const int xk  = a & 7;       // XOR key at read (row & 7 for all fragment rows)
    const size_t scbase = row0 + 64 * wr + a;

    auto stage = [&](int buf, int t) {
#pragma unroll
        for (int c = 0; c < 4; ++c) {
            const int seg = wid * 4 + c;                 // 0..15
            const int row = seg * 8 + l8;
            gll16(Pmat + (size_t)(row0 + row) * NN + t * 64 + ((sc8 ^ l8) << 3),
                  &As[buf][seg * 512]);
        }
#pragma unroll
        for (int c = 0; c < 2; ++c) {
            const int seg = wid * 2 + c;                 // 0..7
            const int row = seg * 8 + l8;
            gll16(featT + (size_t)(col0 + row) * NN + t * 64 + ((sc8 ^ l8) << 3),
                  &Bs[buf][seg * 512]);
        }
    };

    _Float16 pend[4], sc[4];
#pragma unroll
    for (int rf = 0; rf < 4; ++rf) pend[rf] = sc_t[scbase + 16 * rf];

    stage(0, 0);
    __syncthreads();
    int buf = 0;
    for (int t = 0; t < 192; ++t) {
        if ((t & 1) == 0) {
#pragma unroll
            for (int rf = 0; rf < 4; ++rf) sc[rf] = pend[rf];
            const int ktn = (t >> 1) + 1;
            if (ktn < NKT) {
#pragma unroll
                for (int rf = 0; rf < 4; ++rf)
                    pend[rf] = sc_t[(size_t)ktn * NN + scbase + 16 * rf];
            }
        }
        if (t + 1 < 192) stage(buf ^ 1, t + 1);
#pragma unroll
        for (int kk = 0; kk < 2; ++kk) {
            const int c8r = ((kk << 2) + g) ^ xk;        // swizzled read slot
            half8 af[4], bf[2];
#pragma unroll
            for (int rf = 0; rf < 4; ++rf) {
                const int row = 64 * wr + 16 * rf + a;
                af[rf] = *reinterpret_cast<const half8*>(&As[buf][row * 64 + (c8r << 3)]);
                af[rf] = af[rf] * sc[rf];
            }
#pragma unroll
            for (int cf = 0; cf < 2; ++cf) {
                const int row = 32 * wc + 16 * cf + a;
                bf[cf] = *reinterpret_cast<const half8*>(&Bs[buf][row * 64 + (c8r << 3)]);
            }
#pragma unroll
            for (int rf = 0; rf < 4; ++rf)
#pragma unroll
                for (int cf = 0; cf < 2; ++cf)
                    acc[rf][cf] = __builtin_amdgcn_mfma_f32_16x16x32_f16(af[rf], bf[cf], acc[rf][cf], 0, 0, 0);
        }
        __syncthreads();
        buf ^= 1;
    }

    // ---- epilogue: / l ----
#pragma unroll
    for (int rf = 0; rf < 4; ++rf)
#pragma unroll
        for (int r = 0; r < 4; ++r) {
            const int grow = row0 + 64 * wr + 16 * rf + 4 * g + r;
            const float il = 1.0f / l_row[grow];
#pragma unroll
            for (int cf = 0; cf < 2; ++cf) {
                const int gcol = col0 + 32 * wc + 16 * cf + a;
                out[(size_t)grow * FF + gcol] = acc[rf][cf][r] * il;
            }
        }
}

// =====================================================================
// Fallback: round-1 fused flash kernel (verified, 1355 us)
// =====================================================================
constexpr int BM_ = 64;
constexpr int BN_ = 64;
constexpr int KV_STRIDE = 520;

template<bool RH>
__global__ __launch_bounds__(512, 2)
void attn_flash(const float* __restrict__ featf, const _Float16* __restrict__ feath,
                const int* __restrict__ Amat, float* __restrict__ out) {
    __shared__ alignas(16) _Float16 kv[BN_ * KV_STRIDE];
    __shared__ alignas(16) _Float16 pbuf[BM_][72];
    __shared__ alignas(16) float pmax[BM_][2];
    __shared__ alignas(16) float psum[BM_][2];
    __shared__ alignas(16) float m_s[BM_];
    __shared__ alignas(16) float l_s[BM_];
    __shared__ alignas(16) float rscale[BM_];

    const int tid  = threadIdx.x;
    const int lane = tid & 63;
    const int wid  = tid >> 6;
    const int g    = lane >> 4;
    const int a    = lane & 15;
    const int rg   = wid >> 1;
    const int ch   = wid & 1;
    const int qrow0 = blockIdx.x * BM_;

    half8 qf[16];
    {
        const int qr = qrow0 + 16 * rg + a;
#pragma unroll
        for (int ks = 0; ks < 16; ++ks) {
            const int f0 = 32 * ks + 8 * g;
            if constexpr (RH) {
                qf[ks] = *reinterpret_cast<const half8*>(feath + (size_t)qr * FF + f0);
            } else {
                const float* sp = featf + (size_t)qr * FF + f0;
                float4 x = *reinterpret_cast<const float4*>(sp);
                float4 y = *reinterpret_cast<const float4*>(sp + 4);
                half8 h;
                h[0] = (_Float16)x.x; h[1] = (_Float16)x.y; h[2] = (_Float16)x.z; h[3] = (_Float16)x.w;
                h[4] = (_Float16)y.x; h[5] = (_Float16)y.y; h[6] = (_Float16)y.z; h[7] = (_Float16)y.w;
                qf[ks] = h;
            }
        }
    }

    f32x4 acc[4][4];
#pragma unroll
    for (int i = 0; i < 4; ++i)
#pragma unroll
        for (int j = 0; j < 4; ++j) acc[i][j] = f32x4{0.f, 0.f, 0.f, 0.f};

    if (tid < BM_) { m_s[tid] = -INFINITY; l_s[tid] = 0.f; }
    __syncthreads();

    for (int kt = 0; kt < NN / BN_; ++kt) {
        const int key0 = kt * BN_;
#pragma unroll
        for (int i = 0; i < 8; ++i) {
            const int flat8 = tid + i * 512;
            const int key   = flat8 >> 6;
            const int b     = flat8 & 63;
            const int slot  = (b + (key >> 3)) & 63;
            _Float16* dst = &kv[key * KV_STRIDE + slot * 8];
            if constexpr (RH) {
                *reinterpret_cast<half8*>(dst) =
                    *reinterpret_cast<const half8*>(feath + (size_t)(key0 + key) * FF + b * 8);
            } else {
                const float* sp = featf + (size_t)(key0 + key) * FF + b * 8;
                float4 x = *reinterpret_cast<const float4*>(sp);
                float4 y = *reinterpret_cast<const float4*>(sp + 4);
                half8 h;
                h[0] = (_Float16)x.x; h[1] = (_Float16)x.y; h[2] = (_Float16)x.z; h[3] = (_Float16)x.w;
                h[4] = (_Float16)y.x; h[5] = (_Float16)y.y; h[6] = (_Float16)y.z; h[7] = (_Float16)y.w;
                *reinterpret_cast<half8*>(dst) = h;
            }
        }

        int am[2][4];
#pragma unroll
        for (int fc = 0; fc < 2; ++fc)
#pragma unroll
            for (int r = 0; r < 4; ++r) {
                const int arow = qrow0 + 16 * rg + 4 * g + r;
                const int acol = key0 + 32 * ch + 16 * fc + a;
                am[fc][r] = Amat[(size_t)arow * NN + acol];
            }
        __syncthreads();

        f32x4 s0{0.f, 0.f, 0.f, 0.f}, s1{0.f, 0.f, 0.f, 0.f};
        const int bk0 = 32 * ch + a;
        const int bk1 = bk0 + 16;
        const int kb0 = bk0 >> 3;
        const int kb1 = bk1 >> 3;
        const _Float16* kr0 = &kv[bk0 * KV_STRIDE];
        const _Float16* kr1 = &kv[bk1 * KV_STRIDE];
#pragma unroll
        for (int ks = 0; ks < 16; ++ks) {
            const int b = 4 * ks + g;
            const half8 bf0 = *reinterpret_cast<const half8*>(kr0 + (((b + kb0) & 63) << 3));
            const half8 bf1 = *reinterpret_cast<const half8*>(kr1 + (((b + kb1) & 63) << 3));
            s0 = __builtin_amdgcn_mfma_f32_16x16x32_f16(qf[ks], bf0, s0, 0, 0, 0);
            s1 = __builtin_amdgcn_mfma_f32_16x16x32_f16(qf[ks], bf1, s1, 0, 0, 0);
        }

        float sv[2][4];
#pragma unroll
        for (int r = 0; r < 4; ++r) {
            sv[0][r] = (am[0][r] > 0) ? s0[r] : MASK_NEG;
            sv[1][r] = (am[1][r] > 0) ? s1[r] : MASK_NEG;
        }
#pragma unroll
        for (int r = 0; r < 4; ++r) {
            float v = fmaxf(sv[0][r], sv[1][r]);
            v = fmaxf(v, __shfl_xor(v, 1, 16));
            v = fmaxf(v, __shfl_xor(v, 2, 16));
            v = fmaxf(v, __shfl_xor(v, 4, 16));
            v = fmaxf(v, __shfl_xor(v, 8, 16));
            if (a == 0) pmax[16 * rg + 4 * g + r][ch] = v;
        }
        __syncthreads();

#pragma unroll
        for (int r = 0; r < 4; ++r) {
            const int row = 16 * rg + 4 * g + r;
            const float mo = m_s[row];
            const float mn = fmaxf(mo, fmaxf(pmax[row][0], pmax[row][1]));
            const float p0 = __expf(sv[0][r] - mn);
            const float p1 = __expf(sv[1][r] - mn);
            pbuf[row][32 * ch + a]      = (_Float16)p0;
            pbuf[row][32 * ch + 16 + a] = (_Float16)p1;
            float ssum = p0 + p1;
            ssum += __shfl_xor(ssum, 1, 16);
            ssum += __shfl_xor(ssum, 2, 16);
            ssum += __shfl_xor(ssum, 4, 16);
            ssum += __shfl_xor(ssum, 8, 16);
            if (a == 0) psum[row][ch] = ssum;
        }
        __syncthreads();

        if (tid < BM_) {
            const float mo = m_s[tid];
            const float mn = fmaxf(mo, fmaxf(pmax[tid][0], pmax[tid][1]));
            const float sc = __expf(mo - mn);
            l_s[tid] = l_s[tid] * sc + psum[tid][0] + psum[tid][1];
            m_s[tid] = mn;
            rscale[tid] = sc;
        }
        __syncthreads();

#pragma unroll
        for (int rf = 0; rf < 4; ++rf) {
            const float4 scv = *reinterpret_cast<const float4*>(&rscale[16 * rf + 4 * g]);
#pragma unroll
            for (int cf = 0; cf < 4; ++cf) {
                acc[rf][cf][0] *= scv.x; acc[rf][cf][1] *= scv.y;
                acc[rf][cf][2] *= scv.z; acc[rf][cf][3] *= scv.w;
            }
        }
#pragma unroll
        for (int kk = 0; kk < 2; ++kk) {
            half8 af[4];
#pragma unroll
            for (int rf = 0; rf < 4; ++rf)
                af[rf] = *reinterpret_cast<const half8*>(&pbuf[16 * rf + a][32 * kk + 8 * g]);
            const int keybase = 32 * kk + 8 * g;
#pragma unroll
            for (int cf = 0; cf < 4; ++cf) {
                const int col  = 64 * wid + 16 * cf + a;
                const int slot = (((col >> 3) + 4 * kk + g) & 63);
                const _Float16* vb = &kv[(size_t)keybase * KV_STRIDE + (slot << 3) + (col & 7)];
                half8 bf;
#pragma unroll
                for (int j = 0; j < 8; ++j)
                    bf[j] = vb[j * KV_STRIDE];
#pragma unroll
                for (int rf = 0; rf < 4; ++rf)
                    acc[rf][cf] = __builtin_amdgcn_mfma_f32_16x16x32_f16(af[rf], bf, acc[rf][cf], 0, 0, 0);
            }
        }
        __syncthreads();
    }

#pragma unroll
    for (int rf = 0; rf < 4; ++rf) {
        const float4 lv = *reinterpret_cast<const float4*>(&l_s[16 * rf + 4 * g]);
        const float inv[4] = {1.f / lv.x, 1.f / lv.y, 1.f / lv.z, 1.f / lv.w};
#pragma unroll
        for (int cf = 0; cf < 4; ++cf) {
            const int col = 64 * wid + 16 * cf + a;
#pragma unroll
            for (int r = 0; r < 4; ++r) {
                out[(size_t)(qrow0 + 16 * rf + 4 * g + r) * FF + col] = acc[rf][cf][r] * inv[r];
            }
        }
    }
}

extern "C" void kernel_launch(void* const* d_in, const int* in_sizes, int n_in,
                              void* d_out, int out_size, void* d_ws, size_t ws_size,
                              hipStream_t stream) {
    const float* features = (const float*)d_in[0];
    const int*   Amat     = (const int*)d_in[1];
    float*       out      = (float*)d_out;

    // ws layout (fast path, 319.4 MB). Abits + m_t live in d_out scratch (23.6 MB),
    // consumed by gemm1/stats before gemm2 overwrites d_out. Sequential stream.
    const size_t P_bytes   = (size_t)NN * NN * 2;         // 301,989,888
    const size_t f16_bytes = (size_t)NN * FF * 2;         // 12,582,912
    const size_t sct_bytes = (size_t)NKT * NN * 2;        // 2,359,296
    const size_t st_bytes  = (size_t)NKT * NN * 2;        // 2,359,296
    const size_t l_bytes   = (size_t)NN * 4;              // 49,152
    const size_t total     = P_bytes + 2 * f16_bytes + sct_bytes + st_bytes + l_bytes;

    if (ws_size >= total) {
        char* w = (char*)d_ws;
        _Float16* Pmat  = (_Float16*)w;   w += P_bytes;
        _Float16* feath = (_Float16*)w;   w += f16_bytes;
        _Float16* featT = (_Float16*)w;   w += f16_bytes;
        _Float16* sc_t  = (_Float16*)w;   w += sct_bytes;
        _Float16* s_t   = (_Float16*)w;   w += st_bytes;
        float*    l_row = (float*)w;

        uint32_t* Abits = (uint32_t*)d_out;                                    // 18.87 MB
        float*    m_t   = (float*)((char*)d_out + (size_t)NN * NWORDS * 4);    //  4.72 MB

        prepass_fused<<<CMP_BLOCKS + PREP_BLOCKS, 256, 0, stream>>>(Amat, Abits, features, feath, featT);
        gemm1_exp<<<dim3(NN / 128, NN / 128), 256, 0, stream>>>(feath, Abits, Pmat, m_t, s_t);
        stats_kernel<<<NN / 256, 256, 0, stream>>>(m_t, s_t, sc_t, l_row);
        gemm2_scale<<<dim3(NN / 128, FF / 64), 256, 0, stream>>>(Pmat, featT, sc_t, l_row, out);
    } else if (ws_size >= f16_bytes) {
        _Float16* feath = (_Float16*)d_ws;
        cvt_feat_kernel<<<(NN * FF) / (256 * 8), 256, 0, stream>>>(features, feath);
        attn_flash<true><<<NN / BM_, 512, 0, stream>>>(features, feath, Amat, out);
    } else {
        attn_flash<false><<<NN / BM_, 512, 0, stream>>>(features, nullptr, Amat, out);
    }
}